// Round 7
// baseline (1043.494 us; speedup 1.0000x reference)
//
#include <hip/hip_runtime.h>
#include <math.h>

#define NX 256
#define NY 256
#define N_STEPS 300
#define N_CELLS (NX * NY)
#define TILE 16
#define HALO 8
#define LSTR 36              // LDS row stride in floats
#define LROWS 34             // rows -1..32
#define LIDX(rr, cc) (((rr) + 1) * LSTR + ((cc) + 2))
#define NBX 16
#define NBY 16
#define NCHUNK 38            // 38*8 = 304 >= 300; history suppressed past 299

// f32 constants (double-precision fold -> f32)
#define kINV_DX       1280.0f
#define kINV_DY       1280.0f
#define kDT           2.5e-5f
#define kMU           25000.0f
#define kETA          0.1f
#define kDT_OVER_RHO  2.5e-8f
#define kONE_MINUS_BD 0.99999975f
#define kNEG_INV_2SIG2 (-55555.5546875f)   // -1/(2*0.003^2)
#define kDX           7.8125e-4f
#define kEPS          1e-8f

__device__ __forceinline__ float dprof(int k) {
    int m = min(k, NX - 1 - k);
    if (m >= 20) return 1.0f;
    float arg = 3.14159265358979f * (float)(20 - m) / 20.0f;
    return 1.0f - 0.05f * (0.5f + 0.5f * cosf(arg));
}

__global__ __launch_bounds__(512, 1) void persist_kernel(
    const float2* __restrict__ traj,
    float* __restrict__ out,
    float* __restrict__ ws,
    unsigned* __restrict__ seq)      // per-block flags, stride 4 uints
{
    __shared__ float s_vz[2][LROWS * LSTR];

    float* vzS[2]  = { ws + 0 * N_CELLS, ws + 1 * N_CELLS };
    float* sxzS[2] = { ws + 2 * N_CELLS, ws + 3 * N_CELLS };
    float* syzS[2] = { ws + 4 * N_CELLS, ws + 5 * N_CELLS };

    const int tid = threadIdx.x;
    const int bid = blockIdx.x;
    const int bx  = bid & (NBX - 1), by = bid >> 4;
    const int r   = tid >> 4;            // region row, 0..31
    const int c0  = (tid & 15) << 1;     // region col base, 0,2,...,30

    const int gi  = by * TILE + r  - HALO;
    const int gj0 = bx * TILE + c0 - HALO;
    const int g   = gi * NY + gj0;

    const bool rowOK  = (gi >= 0) && (gi < NX);
    const bool colOK  = (gj0 >= 0) && (gj0 < NY);
    const bool inD    = rowOK && colOK;
    const bool fwdX   = (gi < NX - 1);
    const bool fwdY1  = (gj0 + 1 < NY - 1);
    const bool backX  = (gi > 0);
    const bool backY0 = (gj0 > 0);
    const bool haloUp   = (gi - 1 >= 0) && (gi - 1 < NX) && colOK;
    const bool haloLeft = rowOK && (gj0 - 1 >= 0);

    const float dpx   = rowOK ? dprof(gi) : 0.0f;
    const float damp0 = inD ? dpx * dprof(gj0) * kONE_MINUS_BD : 0.0f;
    const float damp1 = inD ? dpx * dprof(gj0 + 1) * kONE_MINUS_BD : 0.0f;
    const float xi    = ((float)gi + 0.5f) * kDX;
    const float yj0   = ((float)gj0 + 0.5f) * kDX;
    const float yj1   = ((float)gj0 + 1.5f) * kDX;

    const bool owned = (r >= HALO) && (r < HALO + TILE) &&
                       (c0 >= HALO) && (c0 + 1 < HALO + TILE);

    // poller lanes: first 8 threads each own one neighbor direction
    bool isPoller = false; int pollIdx = 0;
    if (tid < 8) {
        const int q  = tid + (tid >= 4);     // skip center of 3x3
        const int dy = q / 3 - 1, dx = q % 3 - 1;
        const int nbx_ = bx + dx, nby_ = by + dy;
        if (nbx_ >= 0 && nbx_ < NBX && nby_ >= 0 && nby_ < NBY) {
            isPoller = true;
            pollIdx = (nby_ * NBX + nbx_) * 4;
        }
    }

    // zero LDS once; pads stay zero forever
    for (int idx = tid; idx < 2 * LROWS * LSTR; idx += 512)
        ((float*)s_vz)[idx] = 0.0f;

    // persistent per-thread state (valid for owned threads across all chunks)
    float vz0 = 0.f, vz1 = 0.f, sx0 = 0.f, sx1 = 0.f, sy0 = 0.f, sy1 = 0.f;
    float sxm0 = 0.f, sxm1 = 0.f, symv = 0.f;
    __syncthreads();

    for (int ch = 0; ch < NCHUNK; ++ch) {
        if (ch > 0) {
            // wait: all existing neighbors completed chunk ch-1 (flag >= ch)
            if (isPoller) {
                const unsigned tgt = (unsigned)ch;
                int spins = 0;
                while (__hip_atomic_load(&seq[pollIdx], __ATOMIC_RELAXED,
                                         __HIP_MEMORY_SCOPE_AGENT) < tgt) {
                    __builtin_amdgcn_s_sleep(1);
                    if (++spins > 4096) {   // staleness fallback (should not trigger)
                        while (__hip_atomic_load(&seq[pollIdx], __ATOMIC_ACQUIRE,
                                                 __HIP_MEMORY_SCOPE_AGENT) < tgt)
                            __builtin_amdgcn_s_sleep(16);
                        break;
                    }
                }
            }
            __syncthreads();
            __builtin_amdgcn_fence(__ATOMIC_ACQUIRE, "agent");  // one inv per wave per chunk

            // halo-only reload from state set written by chunk ch-1
            if (!owned) {
                const int rs = (ch - 1) & 1;
                float nvz0 = 0.f, nvz1 = 0.f, nsx0 = 0.f, nsx1 = 0.f;
                float nsy0 = 0.f, nsy1 = 0.f, nsm0 = 0.f, nsm1 = 0.f, nsym = 0.f;
                if (inD) {
                    float2 v2 = *(const float2*)&vzS[rs][g];  nvz0 = v2.x; nvz1 = v2.y;
                    float2 a2 = *(const float2*)&sxzS[rs][g]; nsx0 = a2.x; nsx1 = a2.y;
                    float2 b2 = *(const float2*)&syzS[rs][g]; nsy0 = b2.x; nsy1 = b2.y;
                }
                if (haloUp)   { float2 m2 = *(const float2*)&sxzS[rs][g - NY]; nsm0 = m2.x; nsm1 = m2.y; }
                if (haloLeft) { nsym = syzS[rs][g - 1]; }
                vz0 = nvz0; vz1 = nvz1; sx0 = nsx0; sx1 = nsx1; sy0 = nsy0; sy1 = nsy1;
                sxm0 = nsm0; sxm1 = nsm1; symv = nsym;
            }
        }

        // stage vz into LDS buffer 0
        *(float2*)&s_vz[0][LIDX(r, c0)] = make_float2(vz0, vz1);
        __syncthreads();

        const int t0 = ch * 8;
        float trx[8], tryy[8];
        #pragma unroll
        for (int s = 0; s < 8; ++s) {
            const int t = t0 + s;
            float2 t2 = (t < N_STEPS) ? traj[t] : make_float2(0.f, 0.f);
            trx[s] = t2.x; tryy[s] = t2.y;
        }

        float hv0[8], hv1[8], hs0[8], hs1[8];
        #pragma unroll
        for (int s = 0; s < 8; ++s) {
            const int cur = s & 1, nxt = cur ^ 1;
            const float x_t = trx[s], y_t = tryy[s];

            const float2 vp = *(const float2*)&s_vz[cur][LIDX(r + 1, c0)];
            const float2 vm = *(const float2*)&s_vz[cur][LIDX(r - 1, c0)];
            const float vr2 = s_vz[cur][LIDX(r, c0 + 2)];
            const float vl1 = s_vz[cur][LIDX(r, c0 - 1)];

            const float dvx0 = fwdX  ? (vp.x - vz0) * kINV_DX : 0.0f;
            const float dvx1 = fwdX  ? (vp.y - vz1) * kINV_DX : 0.0f;
            const float dvy0 = (vz1 - vz0) * kINV_DY;
            const float dvy1 = fwdY1 ? (vr2 - vz1) * kINV_DY : 0.0f;

            sx0 += dvx0 * kDT; sx1 += dvx1 * kDT;
            sy0 += dvy0 * kDT; sy1 += dvy1 * kDT;
            const float gx0 = kMU * sx0 + kETA * dvx0;
            const float gx1 = kMU * sx1 + kETA * dvx1;
            const float gy0 = kMU * sy0 + kETA * dvy0;
            const float gy1 = kMU * sy1 + kETA * dvy1;

            const float dxm0 = (vz0 - vm.x) * kINV_DX;
            const float dxm1 = (vz1 - vm.y) * kINV_DX;
            sxm0 += dxm0 * kDT; sxm1 += dxm1 * kDT;
            const float gxm0 = kMU * sxm0 + kETA * dxm0;
            const float gxm1 = kMU * sxm1 + kETA * dxm1;
            const float dym = (vz0 - vl1) * kINV_DY;
            symv += dym * kDT;
            const float gym = kMU * symv + kETA * dym;

            const float dsx0 = backX  ? (gx0 - gxm0) * kINV_DX : 0.0f;
            const float dsx1 = backX  ? (gx1 - gxm1) * kINV_DX : 0.0f;
            const float dsy0 = backY0 ? (gy0 - gym) * kINV_DY : 0.0f;
            const float dsy1 = (gy1 - gy0) * kINV_DY;

            const float rx  = xi - x_t;
            const float ry0 = yj0 - y_t;
            const float ry1 = yj1 - y_t;
            const float src0 = __expf((rx * rx + ry0 * ry0) * kNEG_INV_2SIG2);
            const float src1 = __expf((rx * rx + ry1 * ry1) * kNEG_INV_2SIG2);

            vz0 = (vz0 + kDT_OVER_RHO * (dsx0 + dsy0 + src0)) * damp0;
            vz1 = (vz1 + kDT_OVER_RHO * (dsx1 + dsy1 + src1)) * damp1;

            *(float2*)&s_vz[nxt][LIDX(r, c0)] = make_float2(vz0, vz1);

            hv0[s] = vz0;
            hv1[s] = vz1;
            hs0[s] = sqrtf(gx0 * gx0 + gy0 * gy0 + kEPS);
            hs1[s] = sqrtf(gx1 * gx1 + gy1 * gy1 + kEPS);

            if (s < 7) __syncthreads();
        }

        // state store for neighbors (skip on last chunk)
        if (owned && ch < NCHUNK - 1) {
            const int wsI = ch & 1;
            *(float2*)&vzS[wsI][g]  = make_float2(vz0, vz1);
            *(float2*)&sxzS[wsI][g] = make_float2(sx0, sx1);
            *(float2*)&syzS[wsI][g] = make_float2(sy0, sy1);
        }
        __syncthreads();   // drains all block stores (vmcnt) per __syncthreads semantics
        if (ch < NCHUNK - 1 && tid == 0) {
            __hip_atomic_store(&seq[bid * 4], (unsigned)(ch + 1),
                               __ATOMIC_RELEASE, __HIP_MEMORY_SCOPE_AGENT);
        }

        // history flush after flag publish: drains during next chunk's poll
        if (owned) {
            #pragma unroll
            for (int s = 0; s < 8; ++s) {
                if (t0 + s < N_STEPS) {
                    *(float2*)&out[(size_t)(t0 + s) * N_CELLS + g] =
                        make_float2(hv0[s], hv1[s]);
                    *(float2*)&out[(size_t)(N_STEPS + t0 + s) * N_CELLS + g] =
                        make_float2(hs0[s], hs1[s]);
                }
            }
        }
    }
}

extern "C" void kernel_launch(void* const* d_in, const int* in_sizes, int n_in,
                              void* d_out, int out_size, void* d_ws, size_t ws_size,
                              hipStream_t stream) {
    const float2* traj = (const float2*)d_in[0];
    float* out = (float*)d_out;
    float* ws  = (float*)d_ws;
    unsigned* seq = (unsigned*)((char*)d_ws + (size_t)6 * N_CELLS * sizeof(float));

    // flags must start at 0 on every launch (graph replays don't re-poison)
    hipMemsetAsync(seq, 0, NBX * NBY * 4 * sizeof(unsigned), stream);

    void* args[] = { (void*)&traj, (void*)&out, (void*)&ws, (void*)&seq };
    hipLaunchCooperativeKernel((const void*)persist_kernel,
                               dim3(NBX * NBY), dim3(512), args, 0, stream);
}

// Round 8
// 227.549 us; speedup vs baseline: 4.5858x; 4.5858x over previous
//
#include <hip/hip_runtime.h>
#include <math.h>

#define NX 256
#define NY 256
#define N_STEPS 300
#define N_CELLS (NX * NY)
#define TILE 16
#define HALO 8
#define LSTR 36              // LDS row stride in floats
#define LROWS 34             // rows -1..32
#define LIDX(rr, cc) (((rr) + 1) * LSTR + ((cc) + 2))
#define NBX 16
#define NBY 16
#define NCHUNK 38            // 38*8 = 304 >= 300; history suppressed past 299

// f32 constants (double-precision fold -> f32)
#define kINV_DX       1280.0f
#define kINV_DY       1280.0f
#define kDT           2.5e-5f
#define kMU           25000.0f
#define kETA          0.1f
#define kDT_OVER_RHO  2.5e-8f
#define kONE_MINUS_BD 0.99999975f
#define kNEG_INV_2SIG2 (-55555.5546875f)   // -1/(2*0.003^2)
#define kDX           7.8125e-4f
#define kEPS          1e-8f

__device__ __forceinline__ float dprof(int k) {
    int m = min(k, NX - 1 - k);
    if (m >= 20) return 1.0f;
    float arg = 3.14159265358979f * (float)(20 - m) / 20.0f;
    return 1.0f - 0.05f * (0.5f + 0.5f * cosf(arg));
}

// LLC-coherent (agent-scope, relaxed) accessors — compile to sc-flagged
// global ops with NO cache-maintenance (no buffer_inv / buffer_wbl2).
__device__ __forceinline__ void st_f2(float* p, float a, float b) {
    union { float2 f; unsigned long long u; } x;
    x.f = make_float2(a, b);
    __hip_atomic_store((unsigned long long*)p, x.u,
                       __ATOMIC_RELAXED, __HIP_MEMORY_SCOPE_AGENT);
}
__device__ __forceinline__ float2 ld_f2(const float* p) {
    union { unsigned long long u; float2 f; } x;
    x.u = __hip_atomic_load((const unsigned long long*)p,
                            __ATOMIC_RELAXED, __HIP_MEMORY_SCOPE_AGENT);
    return x.f;
}
__device__ __forceinline__ float ld_f1(const float* p) {
    union { unsigned u; float f; } x;
    x.u = __hip_atomic_load((const unsigned*)p,
                            __ATOMIC_RELAXED, __HIP_MEMORY_SCOPE_AGENT);
    return x.f;
}

__global__ __launch_bounds__(512, 1) void persist_kernel(
    const float2* __restrict__ traj,
    float* __restrict__ out,
    float* __restrict__ ws,
    unsigned* __restrict__ seq)      // per-block flags, stride 4 uints
{
    __shared__ float s_vz[2][LROWS * LSTR];

    float* vzS[2]  = { ws + 0 * N_CELLS, ws + 1 * N_CELLS };
    float* sxzS[2] = { ws + 2 * N_CELLS, ws + 3 * N_CELLS };
    float* syzS[2] = { ws + 4 * N_CELLS, ws + 5 * N_CELLS };

    const int tid = threadIdx.x;
    const int bid = blockIdx.x;
    const int bx  = bid & (NBX - 1), by = bid >> 4;
    const int r   = tid >> 4;            // region row, 0..31
    const int c0  = (tid & 15) << 1;     // region col base, 0,2,...,30

    const int gi  = by * TILE + r  - HALO;
    const int gj0 = bx * TILE + c0 - HALO;
    const int g   = gi * NY + gj0;

    const bool rowOK  = (gi >= 0) && (gi < NX);
    const bool colOK  = (gj0 >= 0) && (gj0 < NY);
    const bool inD    = rowOK && colOK;
    const bool fwdX   = (gi < NX - 1);
    const bool fwdY1  = (gj0 + 1 < NY - 1);
    const bool backX  = (gi > 0);
    const bool backY0 = (gj0 > 0);
    const bool haloUp   = (gi - 1 >= 0) && (gi - 1 < NX) && colOK;
    const bool haloLeft = rowOK && (gj0 - 1 >= 0);

    const float dpx   = rowOK ? dprof(gi) : 0.0f;
    const float damp0 = inD ? dpx * dprof(gj0) * kONE_MINUS_BD : 0.0f;
    const float damp1 = inD ? dpx * dprof(gj0 + 1) * kONE_MINUS_BD : 0.0f;
    const float xi    = ((float)gi + 0.5f) * kDX;
    const float yj0   = ((float)gj0 + 0.5f) * kDX;
    const float yj1   = ((float)gj0 + 1.5f) * kDX;

    const bool owned = (r >= HALO) && (r < HALO + TILE) &&
                       (c0 >= HALO) && (c0 + 1 < HALO + TILE);

    // poller lanes: first 8 threads each own one neighbor direction
    bool isPoller = false; int pollIdx = 0;
    if (tid < 8) {
        const int q  = tid + (tid >= 4);     // skip center of 3x3
        const int dy = q / 3 - 1, dx = q % 3 - 1;
        const int nbx_ = bx + dx, nby_ = by + dy;
        if (nbx_ >= 0 && nbx_ < NBX && nby_ >= 0 && nby_ < NBY) {
            isPoller = true;
            pollIdx = (nby_ * NBX + nbx_) * 4;
        }
    }

    // zero LDS once; pads stay zero forever
    for (int idx = tid; idx < 2 * LROWS * LSTR; idx += 512)
        ((float*)s_vz)[idx] = 0.0f;

    // persistent per-thread state
    float vz0 = 0.f, vz1 = 0.f, sx0 = 0.f, sx1 = 0.f, sy0 = 0.f, sy1 = 0.f;
    float sxm0 = 0.f, sxm1 = 0.f, symv = 0.f;
    __syncthreads();

    for (int ch = 0; ch < NCHUNK; ++ch) {
        if (ch > 0) {
            // wait: all existing neighbors completed chunk ch-1 (flag >= ch)
            if (isPoller) {
                const unsigned tgt = (unsigned)ch;
                while (__hip_atomic_load(&seq[pollIdx], __ATOMIC_RELAXED,
                                         __HIP_MEMORY_SCOPE_AGENT) < tgt) {
                    __builtin_amdgcn_s_sleep(1);
                }
            }
            __syncthreads();   // poll done for all 8 dirs before anyone reads

            // halo-only reload (LLC-coherent loads; owners keep registers)
            if (!owned) {
                const int rs = (ch - 1) & 1;
                float nvz0 = 0.f, nvz1 = 0.f, nsx0 = 0.f, nsx1 = 0.f;
                float nsy0 = 0.f, nsy1 = 0.f, nsm0 = 0.f, nsm1 = 0.f, nsym = 0.f;
                if (inD) {
                    float2 v2 = ld_f2(&vzS[rs][g]);  nvz0 = v2.x; nvz1 = v2.y;
                    float2 a2 = ld_f2(&sxzS[rs][g]); nsx0 = a2.x; nsx1 = a2.y;
                    float2 b2 = ld_f2(&syzS[rs][g]); nsy0 = b2.x; nsy1 = b2.y;
                }
                if (haloUp)   { float2 m2 = ld_f2(&sxzS[rs][g - NY]); nsm0 = m2.x; nsm1 = m2.y; }
                if (haloLeft) { nsym = ld_f1(&syzS[rs][g - 1]); }
                vz0 = nvz0; vz1 = nvz1; sx0 = nsx0; sx1 = nsx1; sy0 = nsy0; sy1 = nsy1;
                sxm0 = nsm0; sxm1 = nsm1; symv = nsym;
            }
        }

        // stage vz into LDS buffer 0
        *(float2*)&s_vz[0][LIDX(r, c0)] = make_float2(vz0, vz1);
        __syncthreads();

        const int t0 = ch * 8;
        float trx[8], tryy[8];
        #pragma unroll
        for (int s = 0; s < 8; ++s) {
            const int t = t0 + s;
            float2 t2 = (t < N_STEPS) ? traj[t] : make_float2(0.f, 0.f);
            trx[s] = t2.x; tryy[s] = t2.y;
        }

        float hv0[8], hv1[8], hs0[8], hs1[8];
        #pragma unroll
        for (int s = 0; s < 8; ++s) {
            const int cur = s & 1, nxt = cur ^ 1;
            const float x_t = trx[s], y_t = tryy[s];

            const float2 vp = *(const float2*)&s_vz[cur][LIDX(r + 1, c0)];
            const float2 vm = *(const float2*)&s_vz[cur][LIDX(r - 1, c0)];
            const float vr2 = s_vz[cur][LIDX(r, c0 + 2)];
            const float vl1 = s_vz[cur][LIDX(r, c0 - 1)];

            const float dvx0 = fwdX  ? (vp.x - vz0) * kINV_DX : 0.0f;
            const float dvx1 = fwdX  ? (vp.y - vz1) * kINV_DX : 0.0f;
            const float dvy0 = (vz1 - vz0) * kINV_DY;
            const float dvy1 = fwdY1 ? (vr2 - vz1) * kINV_DY : 0.0f;

            sx0 += dvx0 * kDT; sx1 += dvx1 * kDT;
            sy0 += dvy0 * kDT; sy1 += dvy1 * kDT;
            const float gx0 = kMU * sx0 + kETA * dvx0;
            const float gx1 = kMU * sx1 + kETA * dvx1;
            const float gy0 = kMU * sy0 + kETA * dvy0;
            const float gy1 = kMU * sy1 + kETA * dvy1;

            const float dxm0 = (vz0 - vm.x) * kINV_DX;
            const float dxm1 = (vz1 - vm.y) * kINV_DX;
            sxm0 += dxm0 * kDT; sxm1 += dxm1 * kDT;
            const float gxm0 = kMU * sxm0 + kETA * dxm0;
            const float gxm1 = kMU * sxm1 + kETA * dxm1;
            const float dym = (vz0 - vl1) * kINV_DY;
            symv += dym * kDT;
            const float gym = kMU * symv + kETA * dym;

            const float dsx0 = backX  ? (gx0 - gxm0) * kINV_DX : 0.0f;
            const float dsx1 = backX  ? (gx1 - gxm1) * kINV_DX : 0.0f;
            const float dsy0 = backY0 ? (gy0 - gym) * kINV_DY : 0.0f;
            const float dsy1 = (gy1 - gy0) * kINV_DY;

            const float rx  = xi - x_t;
            const float ry0 = yj0 - y_t;
            const float ry1 = yj1 - y_t;
            const float src0 = __expf((rx * rx + ry0 * ry0) * kNEG_INV_2SIG2);
            const float src1 = __expf((rx * rx + ry1 * ry1) * kNEG_INV_2SIG2);

            vz0 = (vz0 + kDT_OVER_RHO * (dsx0 + dsy0 + src0)) * damp0;
            vz1 = (vz1 + kDT_OVER_RHO * (dsx1 + dsy1 + src1)) * damp1;

            *(float2*)&s_vz[nxt][LIDX(r, c0)] = make_float2(vz0, vz1);

            hv0[s] = vz0;
            hv1[s] = vz1;
            hs0[s] = sqrtf(gx0 * gx0 + gy0 * gy0 + kEPS);
            hs1[s] = sqrtf(gx1 * gx1 + gy1 * gy1 + kEPS);

            if (s < 7) __syncthreads();
        }

        // state store for neighbors via LLC (skip on last chunk)
        if (owned && ch < NCHUNK - 1) {
            const int wsI = ch & 1;
            st_f2(&vzS[wsI][g],  vz0, vz1);
            st_f2(&sxzS[wsI][g], sx0, sx1);
            st_f2(&syzS[wsI][g], sy0, sy1);
        }
        // hipcc emits s_waitcnt vmcnt(0) before s_barrier for every wave:
        // all sc1 state stores are LLC-visible before any wave passes here.
        __syncthreads();
        if (ch < NCHUNK - 1 && tid == 0) {
            __hip_atomic_store(&seq[bid * 4], (unsigned)(ch + 1),
                               __ATOMIC_RELAXED, __HIP_MEMORY_SCOPE_AGENT);
        }

        // history flush (plain stores, lazy L2 writeback; overlaps next poll)
        if (owned) {
            #pragma unroll
            for (int s = 0; s < 8; ++s) {
                if (t0 + s < N_STEPS) {
                    *(float2*)&out[(size_t)(t0 + s) * N_CELLS + g] =
                        make_float2(hv0[s], hv1[s]);
                    *(float2*)&out[(size_t)(N_STEPS + t0 + s) * N_CELLS + g] =
                        make_float2(hs0[s], hs1[s]);
                }
            }
        }
    }
}

extern "C" void kernel_launch(void* const* d_in, const int* in_sizes, int n_in,
                              void* d_out, int out_size, void* d_ws, size_t ws_size,
                              hipStream_t stream) {
    const float2* traj = (const float2*)d_in[0];
    float* out = (float*)d_out;
    float* ws  = (float*)d_ws;
    unsigned* seq = (unsigned*)((char*)d_ws + (size_t)6 * N_CELLS * sizeof(float));

    // flags must start at 0 on every launch (graph replays don't re-poison)
    hipMemsetAsync(seq, 0, NBX * NBY * 4 * sizeof(unsigned), stream);

    void* args[] = { (void*)&traj, (void*)&out, (void*)&ws, (void*)&seq };
    hipLaunchCooperativeKernel((const void*)persist_kernel,
                               dim3(NBX * NBY), dim3(512), args, 0, stream);
}

// Round 9
// 193.961 us; speedup vs baseline: 5.3799x; 1.1732x over previous
//
#include <hip/hip_runtime.h>
#include <math.h>

typedef float v2f __attribute__((ext_vector_type(2)));

#define NX 256
#define NY 256
#define N_STEPS 300
#define N_CELLS (NX * NY)
#define TILE 16
#define HALO 8
#define LSTR 36              // LDS row stride in floats
#define LROWS 34             // rows -1..32
#define LIDX(rr, cc) (((rr) + 1) * LSTR + ((cc) + 2))
#define NBX 16
#define NBY 16
#define NCHUNK 38            // 38*8 = 304 >= 300; history suppressed past 299

// f32 constants (double-precision fold -> f32)
#define kINV_DX       1280.0f
#define kINV_DY       1280.0f
#define kDT           2.5e-5f
#define kMU           25000.0f
#define kETA          0.1f
#define kDT_OVER_RHO  2.5e-8f
#define kONE_MINUS_BD 0.99999975f
#define kNEG_INV_2SIG2 (-55555.5546875f)   // -1/(2*0.003^2)
#define kDX           7.8125e-4f
#define kEPS          1e-8f
#define kSRC_SKIP_D2  9.0e-4f              // (0.03 m)^2: exp(-55555*9e-4) ~ 2e-22

__device__ __forceinline__ float dprof(int k) {
    int m = min(k, NX - 1 - k);
    if (m >= 20) return 1.0f;
    float arg = 3.14159265358979f * (float)(20 - m) / 20.0f;
    return 1.0f - 0.05f * (0.5f + 0.5f * cosf(arg));
}

// LLC-coherent (agent-scope, relaxed) accessors — no cache-maintenance ops.
__device__ __forceinline__ void st_f2(float* p, v2f v) {
    union { v2f f; unsigned long long u; } x;
    x.f = v;
    __hip_atomic_store((unsigned long long*)p, x.u,
                       __ATOMIC_RELAXED, __HIP_MEMORY_SCOPE_AGENT);
}
__device__ __forceinline__ v2f ld_f2(const float* p) {
    union { unsigned long long u; v2f f; } x;
    x.u = __hip_atomic_load((const unsigned long long*)p,
                            __ATOMIC_RELAXED, __HIP_MEMORY_SCOPE_AGENT);
    return x.f;
}
__device__ __forceinline__ float ld_f1(const float* p) {
    union { unsigned u; float f; } x;
    x.u = __hip_atomic_load((const unsigned*)p,
                            __ATOMIC_RELAXED, __HIP_MEMORY_SCOPE_AGENT);
    return x.f;
}

__global__ __launch_bounds__(512, 1) void persist_kernel(
    const float2* __restrict__ traj,
    float* __restrict__ out,
    float* __restrict__ ws,
    unsigned* __restrict__ seq)      // per-block flags, stride 4 uints
{
    __shared__ float s_vz[2][LROWS * LSTR];

    float* vzS[2]  = { ws + 0 * N_CELLS, ws + 1 * N_CELLS };
    float* sxzS[2] = { ws + 2 * N_CELLS, ws + 3 * N_CELLS };
    float* syzS[2] = { ws + 4 * N_CELLS, ws + 5 * N_CELLS };

    const int tid = threadIdx.x;
    const int bid = blockIdx.x;
    const int bx  = bid & (NBX - 1), by = bid >> 4;
    const int r   = tid >> 4;            // region row, 0..31
    const int c0  = (tid & 15) << 1;     // region col base, 0,2,...,30

    const int gi  = by * TILE + r  - HALO;
    const int gj0 = bx * TILE + c0 - HALO;
    const int g   = gi * NY + gj0;

    const bool rowOK  = (gi >= 0) && (gi < NX);
    const bool colOK  = (gj0 >= 0) && (gj0 < NY);
    const bool inD    = rowOK && colOK;
    const bool haloUp   = (gi - 1 >= 0) && (gi - 1 < NX) && colOK;
    const bool haloLeft = rowOK && (gj0 - 1 >= 0);

    // boundary handling as premultiplied masks (mul-by-0 == reference zero pad)
    const float mxF  = (gi < NX - 1)      ? kINV_DX : 0.0f;   // fwd diff x
    const float myF1 = (gj0 + 1 < NY - 1) ? kINV_DY : 0.0f;   // fwd diff y, 2nd cell
    const float mbX  = (gi > 0)           ? kINV_DX : 0.0f;   // back diff x
    const float mbY0 = (gj0 > 0)          ? kINV_DY : 0.0f;   // back diff y, 1st cell
    const v2f mx2  = {mxF, mxF};
    const v2f my2  = {kINV_DY, myF1};
    const v2f mbx2 = {mbX, mbX};
    const v2f mby2 = {mbY0, kINV_DY};

    const float dpx = rowOK ? dprof(gi) : 0.0f;
    const v2f damp2 = { inD ? dpx * dprof(gj0) * kONE_MINUS_BD : 0.0f,
                        inD ? dpx * dprof(gj0 + 1) * kONE_MINUS_BD : 0.0f };
    const float xi  = ((float)gi + 0.5f) * kDX;
    const v2f   yy2 = { ((float)gj0 + 0.5f) * kDX, ((float)gj0 + 1.5f) * kDX };

    const bool owned = (r >= HALO) && (r < HALO + TILE) &&
                       (c0 >= HALO) && (c0 + 1 < HALO + TILE);

    // region bbox in meters (x = rows/by, y = cols/bx) for source-skip test
    const float xlo = ((float)(by * TILE - HALO) + 0.5f) * kDX;
    const float xhi = ((float)(by * TILE + TILE + HALO - 1) + 0.5f) * kDX;
    const float ylo = ((float)(bx * TILE - HALO) + 0.5f) * kDX;
    const float yhi = ((float)(bx * TILE + TILE + HALO - 1) + 0.5f) * kDX;

    // poller lanes: first 8 threads each own one neighbor direction
    bool isPoller = false; int pollIdx = 0;
    if (tid < 8) {
        const int q  = tid + (tid >= 4);     // skip center of 3x3
        const int dy = q / 3 - 1, dx = q % 3 - 1;
        const int nbx_ = bx + dx, nby_ = by + dy;
        if (nbx_ >= 0 && nbx_ < NBX && nby_ >= 0 && nby_ < NBY) {
            isPoller = true;
            pollIdx = (nby_ * NBX + nbx_) * 4;
        }
    }

    // zero LDS once; pads stay zero forever
    for (int idx = tid; idx < 2 * LROWS * LSTR; idx += 512)
        ((float*)s_vz)[idx] = 0.0f;

    // persistent per-thread state
    v2f V = {0.f, 0.f}, SX = {0.f, 0.f}, SY = {0.f, 0.f}, SXM = {0.f, 0.f};
    float symv = 0.f;
    __syncthreads();

    for (int ch = 0; ch < NCHUNK; ++ch) {
        if (ch > 0) {
            // wait: all existing neighbors completed chunk ch-1 (flag >= ch)
            if (isPoller) {
                const unsigned tgt = (unsigned)ch;
                while (__hip_atomic_load(&seq[pollIdx], __ATOMIC_RELAXED,
                                         __HIP_MEMORY_SCOPE_AGENT) < tgt) {
                    __builtin_amdgcn_s_sleep(1);
                }
            }
            __syncthreads();   // poll done for all 8 dirs before anyone reads

            // halo-only reload (LLC-coherent loads; owners keep registers)
            if (!owned) {
                const int rs = (ch - 1) & 1;
                v2f nV = {0.f, 0.f}, nSX = {0.f, 0.f}, nSY = {0.f, 0.f};
                v2f nSXM = {0.f, 0.f};
                float nsym = 0.f;
                if (inD) {
                    nV  = ld_f2(&vzS[rs][g]);
                    nSX = ld_f2(&sxzS[rs][g]);
                    nSY = ld_f2(&syzS[rs][g]);
                }
                if (haloUp)   nSXM = ld_f2(&sxzS[rs][g - NY]);
                if (haloLeft) nsym = ld_f1(&syzS[rs][g - 1]);
                V = nV; SX = nSX; SY = nSY; SXM = nSXM; symv = nsym;
            }
        }

        // stage vz into LDS buffer 0
        *(v2f*)&s_vz[0][LIDX(r, c0)] = V;
        __syncthreads();

        const int t0 = ch * 8;
        float trx[8], tryy[8];
        #pragma unroll
        for (int s = 0; s < 8; ++s) {
            const int t = t0 + s;
            float2 t2 = (t < N_STEPS) ? traj[t] : make_float2(0.f, 0.f);
            trx[s] = t2.x; tryy[s] = t2.y;
        }

        // chunk-level uniform source-skip: min dist^2 from region bbox
        bool srcNear = false;
        #pragma unroll
        for (int s = 0; s < 8; ++s) {
            const float ddx = fmaxf(fmaxf(xlo - trx[s], trx[s] - xhi), 0.0f);
            const float ddy = fmaxf(fmaxf(ylo - tryy[s], tryy[s] - yhi), 0.0f);
            if (ddx * ddx + ddy * ddy < kSRC_SKIP_D2) srcNear = true;
        }

        v2f hv[8], hs[8];
        #pragma unroll
        for (int s = 0; s < 8; ++s) {
            const int cur = s & 1, nxt = cur ^ 1;

            const v2f vp = *(const v2f*)&s_vz[cur][LIDX(r + 1, c0)];
            const v2f vm = *(const v2f*)&s_vz[cur][LIDX(r - 1, c0)];
            const float vr2 = s_vz[cur][LIDX(r, c0 + 2)];
            const float vl1 = s_vz[cur][LIDX(r, c0 - 1)];

            // forward differences (packed)
            const v2f dvx = (vp - V) * mx2;
            const v2f vsh = {V.y, vr2};
            const v2f dvy = (vsh - V) * my2;

            // own strain/sigma (packed fma)
            SX += dvx * kDT;
            SY += dvy * kDT;
            const v2f GX = SX * kMU + dvx * kETA;
            const v2f GY = SY * kMU + dvy * kETA;

            // halo strain/sigma: row above (packed) + col left (scalar)
            const v2f dxm = (V - vm) * kINV_DX;
            SXM += dxm * kDT;
            const v2f GXM = SXM * kMU + dxm * kETA;
            const float dym = (V.x - vl1) * kINV_DY;
            symv += dym * kDT;
            const float gym = kMU * symv + kETA * dym;

            // stress divergence (packed, boundary via masks)
            const v2f gsh = {gym, GX.x * 0.0f + GY.x};   // {gym, GY.x}
            v2f ds = (GX - GXM) * mbx2 + (GY - gsh) * mby2;

            if (srcNear) {
                const float rx  = xi - trx[s];
                const float rx2 = rx * rx;
                const v2f ry  = yy2 - tryy[s];
                const v2f arg = (ry * ry + rx2) * kNEG_INV_2SIG2;
                ds += (v2f){__expf(arg.x), __expf(arg.y)};
            }

            V = (V + ds * kDT_OVER_RHO) * damp2;

            if (s < 7) *(v2f*)&s_vz[nxt][LIDX(r, c0)] = V;

            hv[s] = V;
            const v2f g2 = GX * GX + GY * GY + kEPS;
            hs[s] = (v2f){__builtin_amdgcn_sqrtf(g2.x),
                          __builtin_amdgcn_sqrtf(g2.y)};

            if (s < 7) __syncthreads();
        }

        // state store for neighbors via LLC (skip on last chunk)
        if (owned && ch < NCHUNK - 1) {
            const int wsI = ch & 1;
            st_f2(&vzS[wsI][g],  V);
            st_f2(&sxzS[wsI][g], SX);
            st_f2(&syzS[wsI][g], SY);
        }
        // hipcc drains vmcnt before s_barrier: state stores LLC-visible here.
        __syncthreads();
        if (ch < NCHUNK - 1 && tid == 0) {
            __hip_atomic_store(&seq[bid * 4], (unsigned)(ch + 1),
                               __ATOMIC_RELAXED, __HIP_MEMORY_SCOPE_AGENT);
        }

        // history flush (plain stores, lazy writeback; overlaps next poll)
        if (owned) {
            #pragma unroll
            for (int s = 0; s < 8; ++s) {
                if (t0 + s < N_STEPS) {
                    *(v2f*)&out[(size_t)(t0 + s) * N_CELLS + g] = hv[s];
                    *(v2f*)&out[(size_t)(N_STEPS + t0 + s) * N_CELLS + g] = hs[s];
                }
            }
        }
    }
}

extern "C" void kernel_launch(void* const* d_in, const int* in_sizes, int n_in,
                              void* d_out, int out_size, void* d_ws, size_t ws_size,
                              hipStream_t stream) {
    const float2* traj = (const float2*)d_in[0];
    float* out = (float*)d_out;
    float* ws  = (float*)d_ws;
    unsigned* seq = (unsigned*)((char*)d_ws + (size_t)6 * N_CELLS * sizeof(float));

    // flags must start at 0 on every launch (graph replays don't re-poison)
    hipMemsetAsync(seq, 0, NBX * NBY * 4 * sizeof(unsigned), stream);

    void* args[] = { (void*)&traj, (void*)&out, (void*)&ws, (void*)&seq };
    hipLaunchCooperativeKernel((const void*)persist_kernel,
                               dim3(NBX * NBY), dim3(512), args, 0, stream);
}